// Round 2
// baseline (304.368 us; speedup 1.0000x reference)
//
#include <hip/hip_runtime.h>
#include <hip/hip_bf16.h>

typedef __attribute__((ext_vector_type(8))) short bf16x8;
typedef __attribute__((ext_vector_type(4))) float f32x4;

#define K_DIM 64
#define CPITCH 72            // shorts per c-row in LDS (144 B; R10-proven 2-way-free frag reads)
#define CROWS 256            // c-rows per band (N-tile)
#define LO_OFF (CROWS * CPITCH)       // 18432 shorts
#define F_OFF  (2 * CROWS * CPITCH)   // 36864 shorts -> float region
#define TOT_SHORTS (F_OFF + 2 * CROWS * 2)  // + 512 f32 = 37888 shorts (75776 B)

// f32x4 -> bf16 hi/lo shorts + sum-of-squares accumulate
__device__ __forceinline__ void split4(const f32x4 v, short* hi, short* lo, float& ss) {
    #pragma unroll
    for (int j = 0; j < 4; ++j) {
        float f = v[j];
        ss = fmaf(f, f, ss);
        __hip_bfloat16 h = __float2bfloat16(f);
        float hf = __bfloat162float(h);
        __hip_bfloat16 l = __float2bfloat16(f - hf);
        hi[j] = *reinterpret_cast<const short*>(&h);
        lo[j] = *reinterpret_cast<const short*>(&l);
    }
}

// ---------------- single fused kernel, 256(M) x 256(N) tile ----------------
// R2 theory: fills (~212 us) are fixed harness overhead (R1: unconditional,
// ws-independent). Kernel portion is vmem-port-bound (~8-12 B/cyc/CU total
// load+store). Doubling the N-tile halves x re-reads: loads 198->128 MB,
// total traffic 466->396 MB, 1.55 MB/CU. 512 thr / 8 waves; wave owns 32
// M-rows; LDS 75.8 KB (hi/lo c-planes @CPITCH=72 + norms) -> 2 blocks/CU.
// launch_bounds(512,4) caps VGPR at 128 (c-stage regs die before x-frags
// live, peak ~90). Main loop / MFMA orientation / store path verbatim from
// the proven kernel.
__global__ __launch_bounds__(512, 4) void rbf_one(
    const float* __restrict__ x, const float* __restrict__ c,
    const float* __restrict__ ls, float* __restrict__ out, int N)
{
    __shared__ __align__(16) short cs[TOT_SHORTS];   // 75776 B

    const int tid  = threadIdx.x;
    const int wave = tid >> 6;
    const int lane = tid & 63;
    const int quad = lane >> 4;
    const int l16  = lane & 15;

    const int band   = blockIdx.x;        // 0..N/256-1
    const int m_base = blockIdx.y << 8;   // 256 rows per block
    const int n_base = band << 8;         // 256 cols per block

    // ---- phase A: stage c-band (256 rows x 64 f32; thread = half-row;
    // each wave covers 8 KB contiguous -> fully coalesced). cv[] dies
    // before the x-frags are loaded, keeping peak VGPR under 128.
    {
        const int crow = tid >> 1, chalf = tid & 1;
        const float* cp = c + (size_t)(n_base + crow) * K_DIM + (chalf << 5);
        f32x4 cv[8];
        #pragma unroll
        for (int i = 0; i < 8; ++i) cv[i] = ((const f32x4*)cp)[i];
        const float lsv = ls[n_base + crow];

        short* hb = cs + crow * CPITCH + (chalf << 5);
        short* lb = hb + LO_OFF;
        float ss = 0.f;
        #pragma unroll
        for (int i = 0; i < 4; ++i) {
            short h[8], l[8];
            split4(cv[2 * i],     h,     l,     ss);
            split4(cv[2 * i + 1], h + 4, l + 4, ss);
            *(bf16x8*)(hb + (i << 3)) = *(bf16x8*)h;
            *(bf16x8*)(lb + (i << 3)) = *(bf16x8*)l;
        }
        ss += __shfl_xor(ss, 1, 64);          // combine the two half-rows
        if (chalf == 0) {
            float* f = (float*)(cs + F_OFF);
            f[crow]         = ss;             // ||c||^2
            f[CROWS + crow] = __expf(-2.0f * lsv);
        }
    }

    // ---- phase B: x fragments f32 -> hi/lo in registers + row norms.
    // Wave owns 32 M-rows -> 2 M-groups.
    const int wbase = m_base + (wave << 5);
    bf16x8 xh0[2], xh1[2], xl0[2], xl1[2];
    float  nxm[2];
    #pragma unroll
    for (int mg = 0; mg < 2; ++mg) {
        const float* xp = x + (size_t)(wbase + (mg << 4) + l16) * K_DIM + (quad << 3);
        f32x4 a0 = *(const f32x4*)xp;
        f32x4 a1 = *(const f32x4*)(xp + 4);
        f32x4 b0 = *(const f32x4*)(xp + 32);
        f32x4 b1 = *(const f32x4*)(xp + 36);
        float ss = 0.f;
        short h[8], l[8];
        split4(a0, h, l, ss); split4(a1, h + 4, l + 4, ss);
        xh0[mg] = *(bf16x8*)h;  xl0[mg] = *(bf16x8*)l;
        split4(b0, h, l, ss); split4(b1, h + 4, l + 4, ss);
        xh1[mg] = *(bf16x8*)h;  xl1[mg] = *(bf16x8*)l;
        ss += __shfl_xor(ss, 16, 64);         // full-row ||x||^2
        ss += __shfl_xor(ss, 32, 64);
        nxm[mg] = ss;
    }

    __syncthreads();

    // ---- main loop: verbatim structure from the proven kernel ----
    const short* hbase = cs;
    const short* lbase = cs + LO_OFF;
    const float* fbase = (const float*)(cs + F_OFF);

    for (int ng = 0; ng < 16; ++ng) {
        const int off = ((ng << 4) + l16) * CPITCH + (quad << 3);
        const bf16x8 ch0 = *(const bf16x8*)(hbase + off);
        const bf16x8 ch1 = *(const bf16x8*)(hbase + off + 32);
        const bf16x8 cl0 = *(const bf16x8*)(lbase + off);
        const bf16x8 cl1 = *(const bf16x8*)(lbase + off + 32);

        const int jc = (ng << 4) + (quad << 2);       // band-local col of 4 outputs
        const f32x4 nc4 = *(const f32x4*)&fbase[jc];
        const f32x4 iv4 = *(const f32x4*)&fbase[CROWS + jc];

        #pragma unroll
        for (int mg = 0; mg < 2; ++mg) {
            f32x4 acc = {0.f, 0.f, 0.f, 0.f};
            acc = __builtin_amdgcn_mfma_f32_16x16x32_bf16(ch0, xh0[mg], acc, 0, 0, 0);
            acc = __builtin_amdgcn_mfma_f32_16x16x32_bf16(ch1, xh1[mg], acc, 0, 0, 0);
            acc = __builtin_amdgcn_mfma_f32_16x16x32_bf16(ch0, xl0[mg], acc, 0, 0, 0);
            acc = __builtin_amdgcn_mfma_f32_16x16x32_bf16(ch1, xl1[mg], acc, 0, 0, 0);
            acc = __builtin_amdgcn_mfma_f32_16x16x32_bf16(cl0, xh0[mg], acc, 0, 0, 0);
            acc = __builtin_amdgcn_mfma_f32_16x16x32_bf16(cl1, xh1[mg], acc, 0, 0, 0);

            f32x4 res;
            #pragma unroll
            for (int r = 0; r < 4; ++r) {
                float sq = fmaxf(nxm[mg] + nc4[r] - 2.0f * acc[r], 0.f);
                res[r] = __expf(-sq * iv4[r]);
            }
            __builtin_nontemporal_store(
                res, (f32x4*)(out + (size_t)(wbase + (mg << 4) + l16) * N + n_base + jc));
        }
    }
}

// ---------------- fallback: fully fused small-tile (R2's passing kernel) ----------------
__device__ __forceinline__ void split8(const float* __restrict__ p,
                                       bf16x8& hi, bf16x8& lo, float& ss) {
    #pragma unroll
    for (int j = 0; j < 8; ++j) {
        float v = p[j];
        ss = fmaf(v, v, ss);
        __hip_bfloat16 h = __float2bfloat16(v);
        float hf = __bfloat162float(h);
        __hip_bfloat16 l = __float2bfloat16(v - hf);
        hi[j] = *reinterpret_cast<const short*>(&h);
        lo[j] = *reinterpret_cast<const short*>(&l);
    }
}

__global__ __launch_bounds__(256) void rbf_fused(
    const float* __restrict__ x, const float* __restrict__ c,
    const float* __restrict__ ls, float* __restrict__ out, int N)
{
    const int wave = threadIdx.x >> 6;
    const int lane = threadIdx.x & 63;
    const int quad = lane >> 4;
    const int l16  = lane & 15;

    const int m_base = (blockIdx.y << 6) + (wave << 4);
    const int n_base = blockIdx.x << 6;

    const int am = m_base + l16;
    const float* xp = x + (size_t)am * K_DIM;
    bf16x8 ahi0, alo0, ahi1, alo1;
    float ssx = 0.f;
    split8(xp + quad * 8,      ahi0, alo0, ssx);
    split8(xp + 32 + quad * 8, ahi1, alo1, ssx);
    ssx += __shfl_xor(ssx, 16, 64);
    ssx += __shfl_xor(ssx, 32, 64);
    float nxr[4];
    #pragma unroll
    for (int r = 0; r < 4; ++r) nxr[r] = __shfl(ssx, quad * 4 + r, 64);

    #pragma unroll
    for (int nt = 0; nt < 4; ++nt) {
        const int n = n_base + nt * 16 + l16;
        const float* cp = c + (size_t)n * K_DIM;
        bf16x8 bhi0, blo0, bhi1, blo1;
        float ssc = 0.f;
        split8(cp + quad * 8,      bhi0, blo0, ssc);
        split8(cp + 32 + quad * 8, bhi1, blo1, ssc);
        ssc += __shfl_xor(ssc, 16, 64);
        ssc += __shfl_xor(ssc, 32, 64);

        f32x4 acc = {0.f, 0.f, 0.f, 0.f};
        acc = __builtin_amdgcn_mfma_f32_16x16x32_bf16(ahi0, bhi0, acc, 0, 0, 0);
        acc = __builtin_amdgcn_mfma_f32_16x16x32_bf16(ahi1, bhi1, acc, 0, 0, 0);
        acc = __builtin_amdgcn_mfma_f32_16x16x32_bf16(ahi0, blo0, acc, 0, 0, 0);
        acc = __builtin_amdgcn_mfma_f32_16x16x32_bf16(ahi1, blo1, acc, 0, 0, 0);
        acc = __builtin_amdgcn_mfma_f32_16x16x32_bf16(alo0, bhi0, acc, 0, 0, 0);
        acc = __builtin_amdgcn_mfma_f32_16x16x32_bf16(alo1, bhi1, acc, 0, 0, 0);

        const float invv = __expf(-2.0f * ls[n]);
        #pragma unroll
        for (int r = 0; r < 4; ++r) {
            const int row = m_base + quad * 4 + r;
            float sq = fmaxf(nxr[r] + ssc - 2.0f * acc[r], 0.f);
            out[(size_t)row * N + n] = __expf(-sq * invv);
        }
    }
}

extern "C" void kernel_launch(void* const* d_in, const int* in_sizes, int n_in,
                              void* d_out, int out_size, void* d_ws, size_t ws_size,
                              hipStream_t stream) {
    const float* x  = (const float*)d_in[0];   // [M,64]
    const float* c  = (const float*)d_in[1];   // [N,64]
    const float* ls = (const float*)d_in[2];   // [N]
    float* out = (float*)d_out;                // [M,N]

    // in_sizes are element counts (verified passing in R0/R1); keep the
    // byte-count fallback interpretation as a guard.
    const int M_e = in_sizes[0] / K_DIM;
    const int N_e = in_sizes[2];
    const int M_b = in_sizes[0] / (K_DIM * 4);
    const int N_b = in_sizes[2] / 4;
    const int Mr = (M_e % 256 == 0) ? M_e : M_b;
    const int Nr = (N_e % 256 == 0) ? N_e : N_b;

    if ((Mr % 256) == 0 && (Nr % 256) == 0) {
        rbf_one<<<dim3(Nr / 256, Mr / 256), 512, 0, stream>>>(x, c, ls, out, Nr);
    } else if ((Mr % 64) == 0 && (Nr % 64) == 0) {
        rbf_fused<<<dim3(Nr / 64, Mr / 64), 256, 0, stream>>>(x, c, ls, out, Nr);
    } else {
        rbf_fused<<<dim3((Nr + 63) / 64, (Mr + 63) / 64), 256, 0, stream>>>(x, c, ls, out, Nr);
    }
}

// Round 3
// 299.533 us; speedup vs baseline: 1.0161x; 1.0161x over previous
//
#include <hip/hip_runtime.h>
#include <hip/hip_bf16.h>

typedef __attribute__((ext_vector_type(8))) short bf16x8;
typedef __attribute__((ext_vector_type(4))) float f32x4;

#define K_DIM 64
#define CPITCH 72            // shorts per c-row in LDS (144 B; R10-proven 2-way-free frag reads)
#define CROWS 256            // c-rows per band (N-tile)
#define LO_OFF (CROWS * CPITCH)       // 18432 shorts
#define F_OFF  (2 * CROWS * CPITCH)   // 36864 shorts -> float region
#define TOT_SHORTS (F_OFF + 2 * CROWS * 2)  // + 512 f32 = 37888 shorts (75776 B)

// f32x4 -> bf16 hi/lo shorts + sum-of-squares accumulate
__device__ __forceinline__ void split4(const f32x4 v, short* hi, short* lo, float& ss) {
    #pragma unroll
    for (int j = 0; j < 4; ++j) {
        float f = v[j];
        ss = fmaf(f, f, ss);
        __hip_bfloat16 h = __float2bfloat16(f);
        float hf = __bfloat162float(h);
        __hip_bfloat16 l = __float2bfloat16(f - hf);
        hi[j] = *reinterpret_cast<const short*>(&h);
        lo[j] = *reinterpret_cast<const short*>(&l);
    }
}

// ---------------- single fused kernel, 256(M) x 256(N) tile ----------------
// R3: R1/R2 proved the load side is irrelevant (466->396 MB moved dur_us by
// 0.08 us). Residual kernel time ~92 us vs 42.5 us pure store roofline
// (fills prove 6.3 TB/s writes). Theory: nontemporal f32x4 stores (64 B per
// row per instruction = half a 128 B line) bypass L2 write-coalescing ->
// HBM read-modify-write -> ~2x write cost. Single change vs R2: plain
// stores (L2 write-allocate merges the two 64 B halves written by
// consecutive ng iterations into full-line evictions).
__global__ __launch_bounds__(512, 4) void rbf_one(
    const float* __restrict__ x, const float* __restrict__ c,
    const float* __restrict__ ls, float* __restrict__ out, int N)
{
    __shared__ __align__(16) short cs[TOT_SHORTS];   // 75776 B

    const int tid  = threadIdx.x;
    const int wave = tid >> 6;
    const int lane = tid & 63;
    const int quad = lane >> 4;
    const int l16  = lane & 15;

    const int band   = blockIdx.x;        // 0..N/256-1
    const int m_base = blockIdx.y << 8;   // 256 rows per block
    const int n_base = band << 8;         // 256 cols per block

    // ---- phase A: stage c-band (256 rows x 64 f32; thread = half-row;
    // each wave covers 8 KB contiguous -> fully coalesced). cv[] dies
    // before the x-frags are loaded, keeping peak VGPR under 128.
    {
        const int crow = tid >> 1, chalf = tid & 1;
        const float* cp = c + (size_t)(n_base + crow) * K_DIM + (chalf << 5);
        f32x4 cv[8];
        #pragma unroll
        for (int i = 0; i < 8; ++i) cv[i] = ((const f32x4*)cp)[i];
        const float lsv = ls[n_base + crow];

        short* hb = cs + crow * CPITCH + (chalf << 5);
        short* lb = hb + LO_OFF;
        float ss = 0.f;
        #pragma unroll
        for (int i = 0; i < 4; ++i) {
            short h[8], l[8];
            split4(cv[2 * i],     h,     l,     ss);
            split4(cv[2 * i + 1], h + 4, l + 4, ss);
            *(bf16x8*)(hb + (i << 3)) = *(bf16x8*)h;
            *(bf16x8*)(lb + (i << 3)) = *(bf16x8*)l;
        }
        ss += __shfl_xor(ss, 1, 64);          // combine the two half-rows
        if (chalf == 0) {
            float* f = (float*)(cs + F_OFF);
            f[crow]         = ss;             // ||c||^2
            f[CROWS + crow] = __expf(-2.0f * lsv);
        }
    }

    // ---- phase B: x fragments f32 -> hi/lo in registers + row norms.
    // Wave owns 32 M-rows -> 2 M-groups.
    const int wbase = m_base + (wave << 5);
    bf16x8 xh0[2], xh1[2], xl0[2], xl1[2];
    float  nxm[2];
    #pragma unroll
    for (int mg = 0; mg < 2; ++mg) {
        const float* xp = x + (size_t)(wbase + (mg << 4) + l16) * K_DIM + (quad << 3);
        f32x4 a0 = *(const f32x4*)xp;
        f32x4 a1 = *(const f32x4*)(xp + 4);
        f32x4 b0 = *(const f32x4*)(xp + 32);
        f32x4 b1 = *(const f32x4*)(xp + 36);
        float ss = 0.f;
        short h[8], l[8];
        split4(a0, h, l, ss); split4(a1, h + 4, l + 4, ss);
        xh0[mg] = *(bf16x8*)h;  xl0[mg] = *(bf16x8*)l;
        split4(b0, h, l, ss); split4(b1, h + 4, l + 4, ss);
        xh1[mg] = *(bf16x8*)h;  xl1[mg] = *(bf16x8*)l;
        ss += __shfl_xor(ss, 16, 64);         // full-row ||x||^2
        ss += __shfl_xor(ss, 32, 64);
        nxm[mg] = ss;
    }

    __syncthreads();

    // ---- main loop: verbatim structure from the proven kernel ----
    const short* hbase = cs;
    const short* lbase = cs + LO_OFF;
    const float* fbase = (const float*)(cs + F_OFF);

    for (int ng = 0; ng < 16; ++ng) {
        const int off = ((ng << 4) + l16) * CPITCH + (quad << 3);
        const bf16x8 ch0 = *(const bf16x8*)(hbase + off);
        const bf16x8 ch1 = *(const bf16x8*)(hbase + off + 32);
        const bf16x8 cl0 = *(const bf16x8*)(lbase + off);
        const bf16x8 cl1 = *(const bf16x8*)(lbase + off + 32);

        const int jc = (ng << 4) + (quad << 2);       // band-local col of 4 outputs
        const f32x4 nc4 = *(const f32x4*)&fbase[jc];
        const f32x4 iv4 = *(const f32x4*)&fbase[CROWS + jc];

        #pragma unroll
        for (int mg = 0; mg < 2; ++mg) {
            f32x4 acc = {0.f, 0.f, 0.f, 0.f};
            acc = __builtin_amdgcn_mfma_f32_16x16x32_bf16(ch0, xh0[mg], acc, 0, 0, 0);
            acc = __builtin_amdgcn_mfma_f32_16x16x32_bf16(ch1, xh1[mg], acc, 0, 0, 0);
            acc = __builtin_amdgcn_mfma_f32_16x16x32_bf16(ch0, xl0[mg], acc, 0, 0, 0);
            acc = __builtin_amdgcn_mfma_f32_16x16x32_bf16(ch1, xl1[mg], acc, 0, 0, 0);
            acc = __builtin_amdgcn_mfma_f32_16x16x32_bf16(cl0, xh0[mg], acc, 0, 0, 0);
            acc = __builtin_amdgcn_mfma_f32_16x16x32_bf16(cl1, xh1[mg], acc, 0, 0, 0);

            f32x4 res;
            #pragma unroll
            for (int r = 0; r < 4; ++r) {
                float sq = fmaxf(nxm[mg] + nc4[r] - 2.0f * acc[r], 0.f);
                res[r] = __expf(-sq * iv4[r]);
            }
            // R3 single change: plain store (was __builtin_nontemporal_store).
            *(f32x4*)(out + (size_t)(wbase + (mg << 4) + l16) * N + n_base + jc) = res;
        }
    }
}

// ---------------- fallback: fully fused small-tile (R2's passing kernel) ----------------
__device__ __forceinline__ void split8(const float* __restrict__ p,
                                       bf16x8& hi, bf16x8& lo, float& ss) {
    #pragma unroll
    for (int j = 0; j < 8; ++j) {
        float v = p[j];
        ss = fmaf(v, v, ss);
        __hip_bfloat16 h = __float2bfloat16(v);
        float hf = __bfloat162float(h);
        __hip_bfloat16 l = __float2bfloat16(v - hf);
        hi[j] = *reinterpret_cast<const short*>(&h);
        lo[j] = *reinterpret_cast<const short*>(&l);
    }
}

__global__ __launch_bounds__(256) void rbf_fused(
    const float* __restrict__ x, const float* __restrict__ c,
    const float* __restrict__ ls, float* __restrict__ out, int N)
{
    const int wave = threadIdx.x >> 6;
    const int lane = threadIdx.x & 63;
    const int quad = lane >> 4;
    const int l16  = lane & 15;

    const int m_base = (blockIdx.y << 6) + (wave << 4);
    const int n_base = blockIdx.x << 6;

    const int am = m_base + l16;
    const float* xp = x + (size_t)am * K_DIM;
    bf16x8 ahi0, alo0, ahi1, alo1;
    float ssx = 0.f;
    split8(xp + quad * 8,      ahi0, alo0, ssx);
    split8(xp + 32 + quad * 8, ahi1, alo1, ssx);
    ssx += __shfl_xor(ssx, 16, 64);
    ssx += __shfl_xor(ssx, 32, 64);
    float nxr[4];
    #pragma unroll
    for (int r = 0; r < 4; ++r) nxr[r] = __shfl(ssx, quad * 4 + r, 64);

    #pragma unroll
    for (int nt = 0; nt < 4; ++nt) {
        const int n = n_base + nt * 16 + l16;
        const float* cp = c + (size_t)n * K_DIM;
        bf16x8 bhi0, blo0, bhi1, blo1;
        float ssc = 0.f;
        split8(cp + quad * 8,      bhi0, blo0, ssc);
        split8(cp + 32 + quad * 8, bhi1, blo1, ssc);
        ssc += __shfl_xor(ssc, 16, 64);
        ssc += __shfl_xor(ssc, 32, 64);

        f32x4 acc = {0.f, 0.f, 0.f, 0.f};
        acc = __builtin_amdgcn_mfma_f32_16x16x32_bf16(ahi0, bhi0, acc, 0, 0, 0);
        acc = __builtin_amdgcn_mfma_f32_16x16x32_bf16(ahi1, bhi1, acc, 0, 0, 0);
        acc = __builtin_amdgcn_mfma_f32_16x16x32_bf16(ahi0, blo0, acc, 0, 0, 0);
        acc = __builtin_amdgcn_mfma_f32_16x16x32_bf16(ahi1, blo1, acc, 0, 0, 0);
        acc = __builtin_amdgcn_mfma_f32_16x16x32_bf16(alo0, bhi0, acc, 0, 0, 0);
        acc = __builtin_amdgcn_mfma_f32_16x16x32_bf16(alo1, bhi1, acc, 0, 0, 0);

        const float invv = __expf(-2.0f * ls[n]);
        #pragma unroll
        for (int r = 0; r < 4; ++r) {
            const int row = m_base + quad * 4 + r;
            float sq = fmaxf(nxr[r] + ssc - 2.0f * acc[r], 0.f);
            out[(size_t)row * N + n] = __expf(-sq * invv);
        }
    }
}

extern "C" void kernel_launch(void* const* d_in, const int* in_sizes, int n_in,
                              void* d_out, int out_size, void* d_ws, size_t ws_size,
                              hipStream_t stream) {
    const float* x  = (const float*)d_in[0];   // [M,64]
    const float* c  = (const float*)d_in[1];   // [N,64]
    const float* ls = (const float*)d_in[2];   // [N]
    float* out = (float*)d_out;                // [M,N]

    // in_sizes are element counts (verified passing in R0/R1); keep the
    // byte-count fallback interpretation as a guard.
    const int M_e = in_sizes[0] / K_DIM;
    const int N_e = in_sizes[2];
    const int M_b = in_sizes[0] / (K_DIM * 4);
    const int N_b = in_sizes[2] / 4;
    const int Mr = (M_e % 256 == 0) ? M_e : M_b;
    const int Nr = (N_e % 256 == 0) ? N_e : N_b;

    if ((Mr % 256) == 0 && (Nr % 256) == 0) {
        rbf_one<<<dim3(Nr / 256, Mr / 256), 512, 0, stream>>>(x, c, ls, out, Nr);
    } else if ((Mr % 64) == 0 && (Nr % 64) == 0) {
        rbf_fused<<<dim3(Nr / 64, Mr / 64), 256, 0, stream>>>(x, c, ls, out, Nr);
    } else {
        rbf_fused<<<dim3((Nr + 63) / 64, (Mr + 63) / 64), 256, 0, stream>>>(x, c, ls, out, Nr);
    }
}

// Round 4
// 271.910 us; speedup vs baseline: 1.1194x; 1.1016x over previous
//
#include <hip/hip_runtime.h>
#include <hip/hip_bf16.h>

typedef __attribute__((ext_vector_type(8))) short bf16x8;
typedef __attribute__((ext_vector_type(4))) float f32x4;

#define K_DIM 64
#define CPITCH 72            // shorts per c-row in LDS (144 B; R10-proven 2-way-free frag reads)
#define CROWS 256            // c-rows per band (N-tile)
#define LO_OFF (CROWS * CPITCH)       // 18432 shorts
#define F_OFF  (2 * CROWS * CPITCH)   // 36864 shorts -> float region
#define TOT_SHORTS (F_OFF + 2 * CROWS * 2)  // + 512 f32 = 37888 shorts (75776 B)

// f32x4 -> bf16 hi/lo shorts + sum-of-squares accumulate
__device__ __forceinline__ void split4(const f32x4 v, short* hi, short* lo, float& ss) {
    #pragma unroll
    for (int j = 0; j < 4; ++j) {
        float f = v[j];
        ss = fmaf(f, f, ss);
        __hip_bfloat16 h = __float2bfloat16(f);
        float hf = __bfloat162float(h);
        __hip_bfloat16 l = __float2bfloat16(f - hf);
        hi[j] = *reinterpret_cast<const short*>(&h);
        lo[j] = *reinterpret_cast<const short*>(&l);
    }
}

// pull a full f32x4 from source lane (addrB = srclane*4) via ds_bpermute
__device__ __forceinline__ f32x4 pull4(int addrB, f32x4 v) {
    f32x4 r;
    #pragma unroll
    for (int k = 0; k < 4; ++k)
        r[k] = __int_as_float(__builtin_amdgcn_ds_bpermute(addrB, __float_as_int(v[k])));
    return r;
}

// ---------------- single fused kernel, 256(M) x 256(N) tile ----------------
// R4: loads are L2/L3-resident (c=1MB, x=4MB) -> true HBM traffic ~= 268 MB
// of stores. Residual kernel time ~85 us = exactly 2x the 42.5 us store
// roofline. Theory: 64 B half-line stores (16x16 tile = 16 rows x 64 B)
// trigger L2 write-allocate RFO -> +268 MB of useless HBM reads. Fix: pair
// adjacent ng tiles and ds_bpermute the results so each store instruction
// covers 8 rows x 128 B FULL lines. Bytes/instr counts unchanged; the only
// new cost is 256 loop-invariant-addressed bpermutes per wave.
__global__ __launch_bounds__(512, 4) void rbf_one(
    const float* __restrict__ x, const float* __restrict__ c,
    const float* __restrict__ ls, float* __restrict__ out, int N)
{
    __shared__ __align__(16) short cs[TOT_SHORTS];   // 75776 B

    const int tid  = threadIdx.x;
    const int wave = tid >> 6;
    const int lane = tid & 63;
    const int quad = lane >> 4;
    const int l16  = lane & 15;

    const int band   = blockIdx.x;        // 0..N/256-1
    const int m_base = blockIdx.y << 8;   // 256 rows per block
    const int n_base = band << 8;         // 256 cols per block

    // ---- phase A: stage c-band (256 rows x 64 f32; thread = half-row) ----
    {
        const int crow = tid >> 1, chalf = tid & 1;
        const float* cp = c + (size_t)(n_base + crow) * K_DIM + (chalf << 5);
        f32x4 cv[8];
        #pragma unroll
        for (int i = 0; i < 8; ++i) cv[i] = ((const f32x4*)cp)[i];
        const float lsv = ls[n_base + crow];

        short* hb = cs + crow * CPITCH + (chalf << 5);
        short* lb = hb + LO_OFF;
        float ss = 0.f;
        #pragma unroll
        for (int i = 0; i < 4; ++i) {
            short h[8], l[8];
            split4(cv[2 * i],     h,     l,     ss);
            split4(cv[2 * i + 1], h + 4, l + 4, ss);
            *(bf16x8*)(hb + (i << 3)) = *(bf16x8*)h;
            *(bf16x8*)(lb + (i << 3)) = *(bf16x8*)l;
        }
        ss += __shfl_xor(ss, 1, 64);          // combine the two half-rows
        if (chalf == 0) {
            float* f = (float*)(cs + F_OFF);
            f[crow]         = ss;             // ||c||^2
            f[CROWS + crow] = __expf(-2.0f * lsv);
        }
    }

    // ---- phase B: x fragments f32 -> hi/lo in registers + row norms ----
    const int wbase = m_base + (wave << 5);
    bf16x8 xh0[2], xh1[2], xl0[2], xl1[2];
    float  nxm[2];
    #pragma unroll
    for (int mg = 0; mg < 2; ++mg) {
        const float* xp = x + (size_t)(wbase + (mg << 4) + l16) * K_DIM + (quad << 3);
        f32x4 a0 = *(const f32x4*)xp;
        f32x4 a1 = *(const f32x4*)(xp + 4);
        f32x4 b0 = *(const f32x4*)(xp + 32);
        f32x4 b1 = *(const f32x4*)(xp + 36);
        float ss = 0.f;
        short h[8], l[8];
        split4(a0, h, l, ss); split4(a1, h + 4, l + 4, ss);
        xh0[mg] = *(bf16x8*)h;  xl0[mg] = *(bf16x8*)l;
        split4(b0, h, l, ss); split4(b1, h + 4, l + 4, ss);
        xh1[mg] = *(bf16x8*)h;  xl1[mg] = *(bf16x8*)l;
        ss += __shfl_xor(ss, 16, 64);         // full-row ||x||^2
        ss += __shfl_xor(ss, 32, 64);
        nxm[mg] = ss;
    }

    __syncthreads();

    // ---- main loop: tile-pair structure; math identical to R3 ----
    const short* hbase = cs;
    const short* lbase = cs + 9216 * 0 + LO_OFF;
    const float* fbase = (const float*)(cs + F_OFF);

    // loop-invariant permute/store geometry
    const int c8 = lane & 7, r8 = lane >> 3;
    const int s1 = ((c8 & 3) << 4) + r8;   // source lane for store 1
    const int a1 = s1 << 2;                // ds_bpermute byte addr
    const int a2 = (s1 + 8) << 2;          // store 2 (rows +8)
    const int colb = c8 << 2;              // col offset within 32-col span

    for (int t = 0; t < 8; ++t) {
        f32x4 resA[2], resB[2];
        #pragma unroll
        for (int half = 0; half < 2; ++half) {
            const int ng = (t << 1) + half;
            const int off = ((ng << 4) + l16) * CPITCH + (quad << 3);
            const bf16x8 ch0 = *(const bf16x8*)(hbase + off);
            const bf16x8 ch1 = *(const bf16x8*)(hbase + off + 32);
            const bf16x8 cl0 = *(const bf16x8*)(lbase + off);
            const bf16x8 cl1 = *(const bf16x8*)(lbase + off + 32);

            const int jc = (ng << 4) + (quad << 2);
            const f32x4 nc4 = *(const f32x4*)&fbase[jc];
            const f32x4 iv4 = *(const f32x4*)&fbase[CROWS + jc];

            #pragma unroll
            for (int mg = 0; mg < 2; ++mg) {
                f32x4 acc = {0.f, 0.f, 0.f, 0.f};
                acc = __builtin_amdgcn_mfma_f32_16x16x32_bf16(ch0, xh0[mg], acc, 0, 0, 0);
                acc = __builtin_amdgcn_mfma_f32_16x16x32_bf16(ch1, xh1[mg], acc, 0, 0, 0);
                acc = __builtin_amdgcn_mfma_f32_16x16x32_bf16(ch0, xl0[mg], acc, 0, 0, 0);
                acc = __builtin_amdgcn_mfma_f32_16x16x32_bf16(ch1, xl1[mg], acc, 0, 0, 0);
                acc = __builtin_amdgcn_mfma_f32_16x16x32_bf16(cl0, xh0[mg], acc, 0, 0, 0);
                acc = __builtin_amdgcn_mfma_f32_16x16x32_bf16(cl1, xh1[mg], acc, 0, 0, 0);

                f32x4 res;
                #pragma unroll
                for (int r = 0; r < 4; ++r) {
                    float sq = fmaxf(nxm[mg] + nc4[r] - 2.0f * acc[r], 0.f);
                    res[r] = __expf(-sq * iv4[r]);
                }
                if (half == 0) resA[mg] = res; else resB[mg] = res;
            }
        }

        // ---- permuted full-line stores: 8 rows x 128 B per instruction ----
        const size_t cb = (size_t)(n_base + (t << 5) + colb);
        #pragma unroll
        for (int mg = 0; mg < 2; ++mg) {
            const f32x4 pa1 = pull4(a1, resA[mg]);
            const f32x4 pb1 = pull4(a1, resB[mg]);
            const f32x4 pa2 = pull4(a2, resA[mg]);
            const f32x4 pb2 = pull4(a2, resB[mg]);
            f32x4 v1, v2;
            #pragma unroll
            for (int k = 0; k < 4; ++k) {
                v1[k] = (c8 < 4) ? pa1[k] : pb1[k];
                v2[k] = (c8 < 4) ? pa2[k] : pb2[k];
            }
            const size_t rb = (size_t)(wbase + (mg << 4)) * N;
            *(f32x4*)(out + rb + (size_t)r8 * N + cb)       = v1;
            *(f32x4*)(out + rb + (size_t)(8 + r8) * N + cb) = v2;
        }
    }
}

// ---------------- fallback: fully fused small-tile (R2's passing kernel) ----------------
__device__ __forceinline__ void split8(const float* __restrict__ p,
                                       bf16x8& hi, bf16x8& lo, float& ss) {
    #pragma unroll
    for (int j = 0; j < 8; ++j) {
        float v = p[j];
        ss = fmaf(v, v, ss);
        __hip_bfloat16 h = __float2bfloat16(v);
        float hf = __bfloat162float(h);
        __hip_bfloat16 l = __float2bfloat16(v - hf);
        hi[j] = *reinterpret_cast<const short*>(&h);
        lo[j] = *reinterpret_cast<const short*>(&l);
    }
}

__global__ __launch_bounds__(256) void rbf_fused(
    const float* __restrict__ x, const float* __restrict__ c,
    const float* __restrict__ ls, float* __restrict__ out, int N)
{
    const int wave = threadIdx.x >> 6;
    const int lane = threadIdx.x & 63;
    const int quad = lane >> 4;
    const int l16  = lane & 15;

    const int m_base = (blockIdx.y << 6) + (wave << 4);
    const int n_base = blockIdx.x << 6;

    const int am = m_base + l16;
    const float* xp = x + (size_t)am * K_DIM;
    bf16x8 ahi0, alo0, ahi1, alo1;
    float ssx = 0.f;
    split8(xp + quad * 8,      ahi0, alo0, ssx);
    split8(xp + 32 + quad * 8, ahi1, alo1, ssx);
    ssx += __shfl_xor(ssx, 16, 64);
    ssx += __shfl_xor(ssx, 32, 64);
    float nxr[4];
    #pragma unroll
    for (int r = 0; r < 4; ++r) nxr[r] = __shfl(ssx, quad * 4 + r, 64);

    #pragma unroll
    for (int nt = 0; nt < 4; ++nt) {
        const int n = n_base + nt * 16 + l16;
        const float* cp = c + (size_t)n * K_DIM;
        bf16x8 bhi0, blo0, bhi1, blo1;
        float ssc = 0.f;
        split8(cp + quad * 8,      bhi0, blo0, ssc);
        split8(cp + 32 + quad * 8, bhi1, blo1, ssc);
        ssc += __shfl_xor(ssc, 16, 64);
        ssc += __shfl_xor(ssc, 32, 64);

        f32x4 acc = {0.f, 0.f, 0.f, 0.f};
        acc = __builtin_amdgcn_mfma_f32_16x16x32_bf16(ahi0, bhi0, acc, 0, 0, 0);
        acc = __builtin_amdgcn_mfma_f32_16x16x32_bf16(ahi1, bhi1, acc, 0, 0, 0);
        acc = __builtin_amdgcn_mfma_f32_16x16x32_bf16(ahi0, blo0, acc, 0, 0, 0);
        acc = __builtin_amdgcn_mfma_f32_16x16x32_bf16(ahi1, blo1, acc, 0, 0, 0);
        acc = __builtin_amdgcn_mfma_f32_16x16x32_bf16(alo0, bhi0, acc, 0, 0, 0);
        acc = __builtin_amdgcn_mfma_f32_16x16x32_bf16(alo1, bhi1, acc, 0, 0, 0);

        const float invv = __expf(-2.0f * ls[n]);
        #pragma unroll
        for (int r = 0; r < 4; ++r) {
            const int row = m_base + quad * 4 + r;
            float sq = fmaxf(nxr[r] + ssc - 2.0f * acc[r], 0.f);
            out[(size_t)row * N + n] = __expf(-sq * invv);
        }
    }
}

extern "C" void kernel_launch(void* const* d_in, const int* in_sizes, int n_in,
                              void* d_out, int out_size, void* d_ws, size_t ws_size,
                              hipStream_t stream) {
    const float* x  = (const float*)d_in[0];   // [M,64]
    const float* c  = (const float*)d_in[1];   // [N,64]
    const float* ls = (const float*)d_in[2];   // [N]
    float* out = (float*)d_out;                // [M,N]

    // in_sizes are element counts (verified passing in R0/R1); keep the
    // byte-count fallback interpretation as a guard.
    const int M_e = in_sizes[0] / K_DIM;
    const int N_e = in_sizes[2];
    const int M_b = in_sizes[0] / (K_DIM * 4);
    const int N_b = in_sizes[2] / 4;
    const int Mr = (M_e % 256 == 0) ? M_e : M_b;
    const int Nr = (N_e % 256 == 0) ? N_e : N_b;

    if ((Mr % 256) == 0 && (Nr % 256) == 0) {
        rbf_one<<<dim3(Nr / 256, Mr / 256), 512, 0, stream>>>(x, c, ls, out, Nr);
    } else if ((Mr % 64) == 0 && (Nr % 64) == 0) {
        rbf_fused<<<dim3(Nr / 64, Mr / 64), 256, 0, stream>>>(x, c, ls, out, Nr);
    } else {
        rbf_fused<<<dim3((Nr + 63) / 64, (Mr + 63) / 64), 256, 0, stream>>>(x, c, ls, out, Nr);
    }
}